// Round 19
// baseline (25.680 us; speedup 1.0000x reference)
//
#include <hip/hip_runtime.h>

#define NE 19
#define CIN 64
#define Z1T_STRIDE 80          // bytes per Z1T row (32 bf16 of 40); 16B-aligned, 2-way banks = free
#define SLICE 5120             // one Z1T slice per block (64*80)
#define WS_AFRAG 16384         // ws: [0,16K) Wc B-frags; [16K,18K) A-mix A-frags

typedef float f32x4 __attribute__((ext_vector_type(4)));
typedef __bf16 bf16x4 __attribute__((ext_vector_type(4)));
typedef __bf16 bf16x8 __attribute__((ext_vector_type(8)));

// Native casts -> v_cvt_pk_bf16_f32 (1 instr / 2 values)
__device__ __forceinline__ bf16x8 packW(const float* q) {
  f32x4 a = *(const f32x4*)q;
  f32x4 b = *(const f32x4*)(q + 4);
  bf16x8 h;
  h[0]=(__bf16)a[0]; h[1]=(__bf16)a[1]; h[2]=(__bf16)a[2]; h[3]=(__bf16)a[3];
  h[4]=(__bf16)b[0]; h[5]=(__bf16)b[1]; h[6]=(__bf16)b[2]; h[7]=(__bf16)b[3];
  return h;
}

// K1 (5 blocks): pack Wc B-frags + softplus(A) A-frags (bf16) into workspace.
// B-frag fid = ((p*2+kt)*4+nt)*64+lane, p0=Wrel p1=Wroot.
__global__ void prep_kernel(const float* __restrict__ ew,
                            const float* __restrict__ Wrel,
                            const float* __restrict__ Wroot,
                            unsigned char* __restrict__ ws) {
  const int t = threadIdx.x, bid = blockIdx.x;
  if (bid < 4) {
    int fid = bid * 256 + t;
    int p = fid >> 9, kt = (fid >> 8) & 1, nt = (fid >> 6) & 3, lane = fid & 63;
    const float* Wsrc = p ? Wroot : Wrel;
    *(bf16x8*)(ws + fid * 16) =
        packW(Wsrc + (nt * 16 + (lane & 15)) * CIN + kt * 32 + (lane >> 4) * 8);
  } else if (t < 128) {
    // A-mix A-frag: lane holds A[mt*16+(lane&15)][k=(lane>>4)*8+b], A[i][j]=sp(ew[j*19+i])
    int mt = t >> 6, lane = t & 63;
    int row = mt * 16 + (lane & 15);
    bf16x8 h;
    #pragma unroll
    for (int b = 0; b < 8; ++b) {
      int k = (lane >> 4) * 8 + b;
      float v = 0.0f;
      if (row < NE && k < NE) {
        float z = ew[k * NE + row];
        v = fmaxf(z, 0.0f) + log1pf(expf(-fabsf(z)));
      }
      h[b] = (__bf16)v;
    }
    *(bf16x8*)(ws + WS_AFRAG + t * 16) = h;
  }
}

// K2: 4096 single-wave blocks, 2 graphs/wave (lookahead-1 x prefetch), one
// LDS slice reused sequentially (same-wave program order -> race-free), zero
// barriers, all compute in MFMA, frags hoisted once, direct 64B-segment
// global stores (R17/R18: no write inflation).
// out = A@(X@Wrel^T) + X@Wroot^T + bias
// launch_bounds (64,2): VGPR cap 128 (cap = 256/min_waves; >=4 clamps to 64
// and spills — R12).
__global__ __launch_bounds__(64, 2) void gconv_kernel(
    const float* __restrict__ x, const float* __restrict__ bias,
    const unsigned char* __restrict__ ws, float* __restrict__ out)
{
  __shared__ __align__(16) unsigned char sl[SLICE];  // 5120 B -> 16 blocks/CU by grid

  const int lane = threadIdx.x & 63;
  const int g0 = blockIdx.x * 2;
  const int lr = lane & 15, hg = lane >> 4;
  const bf16x8* frB = (const bf16x8*)ws;

  // ---- x prefetch for both graphs (HBM latency starts now)
  auto LOADAF = [&](bf16x8 af[2][2], int g) {
    const float* xg = x + (long long)g * NE * CIN;
    #pragma unroll
    for (int mt = 0; mt < 2; ++mt) {
      int rr = mt * 16 + lr; if (rr > NE - 1) rr = NE - 1;  // dup rows, stores guarded
      const float* xr = xg + rr * CIN + hg * 8;
      #pragma unroll
      for (int kt = 0; kt < 2; ++kt) af[mt][kt] = packW(xr + kt * 32);
    }
  };
  bf16x8 afa[2][2], afb[2][2];
  LOADAF(afa, g0);
  LOADAF(afb, g0 + 1);

  // ---- frags ONCE per wave (18 L2-hot loads; arrive under the x latency)
  bf16x8 bfa[8], bfb[8];
  #pragma unroll
  for (int i = 0; i < 8; ++i) bfa[i] = frB[i * 64 + lane];
  #pragma unroll
  for (int i = 0; i < 8; ++i) bfb[i] = frB[(8 + i) * 64 + lane];
  const bf16x8 afm0 = frB[1024 + lane];
  const bf16x8 afm1 = frB[1088 + lane];
  float biasv[4];
  #pragma unroll
  for (int nt = 0; nt < 4; ++nt) biasv[nt] = bias[nt * 16 + lr];

  // ---- per-graph pipeline: half1 -> Z1T -> half2 -> mix -> DIRECT store
  auto PROC = [&](bf16x8 af[2][2], unsigned char* z1, int g) {
    // half 1: Z1 = X @ Wrel^T
    f32x4 zacc[2][4];
    #pragma unroll
    for (int mt = 0; mt < 2; ++mt)
      #pragma unroll
      for (int nt = 0; nt < 4; ++nt) { zacc[mt][nt][0]=0.f; zacc[mt][nt][1]=0.f; zacc[mt][nt][2]=0.f; zacc[mt][nt][3]=0.f; }
    #pragma unroll
    for (int nt = 0; nt < 4; ++nt)
      #pragma unroll
      for (int mt = 0; mt < 2; ++mt) {
        zacc[mt][nt] = __builtin_amdgcn_mfma_f32_16x16x32_bf16(
            af[mt][0], bfa[nt], zacc[mt][nt], 0, 0, 0);
        zacc[mt][nt] = __builtin_amdgcn_mfma_f32_16x16x32_bf16(
            af[mt][1], bfa[4 + nt], zacc[mt][nt], 0, 0, 0);
      }
    // bounce Z1 -> Z1T[c][j] bf16 (j 19..31 zeroed), 8 ds_write_b64
    #pragma unroll
    for (int nt = 0; nt < 4; ++nt) {
      int c = nt * 16 + lr;
      bf16x4 h0;
      #pragma unroll
      for (int b = 0; b < 4; ++b) h0[b] = (__bf16)zacc[0][nt][b];
      *(bf16x4*)(z1 + c * Z1T_STRIDE + hg * 8) = h0;
      bf16x4 h1;
      #pragma unroll
      for (int b = 0; b < 4; ++b) {
        int j = 16 + hg * 4 + b;
        h1[b] = (j < NE) ? (__bf16)zacc[1][nt][b] : (__bf16)0.0f;
      }
      *(bf16x4*)(z1 + c * Z1T_STRIDE + 32 + hg * 8) = h1;
    }

    // half 2: acc = X @ Wroot^T (independent of the bounce -> overlaps it)
    f32x4 acc[2][4];
    #pragma unroll
    for (int mt = 0; mt < 2; ++mt)
      #pragma unroll
      for (int nt = 0; nt < 4; ++nt) { acc[mt][nt][0]=0.f; acc[mt][nt][1]=0.f; acc[mt][nt][2]=0.f; acc[mt][nt][3]=0.f; }
    #pragma unroll
    for (int nt = 0; nt < 4; ++nt)
      #pragma unroll
      for (int mt = 0; mt < 2; ++mt) {
        acc[mt][nt] = __builtin_amdgcn_mfma_f32_16x16x32_bf16(
            af[mt][0], bfb[nt], acc[mt][nt], 0, 0, 0);
        acc[mt][nt] = __builtin_amdgcn_mfma_f32_16x16x32_bf16(
            af[mt][1], bfb[4 + nt], acc[mt][nt], 0, 0, 0);
      }
    // mix as MFMA: acc += A @ Z1
    #pragma unroll
    for (int nt = 0; nt < 4; ++nt) {
      bf16x8 zf = *(const bf16x8*)(z1 + (nt * 16 + lr) * Z1T_STRIDE + hg * 16);
      acc[0][nt] = __builtin_amdgcn_mfma_f32_16x16x32_bf16(afm0, zf, acc[0][nt], 0, 0, 0);
      acc[1][nt] = __builtin_amdgcn_mfma_f32_16x16x32_bf16(afm1, zf, acc[1][nt], 0, 0, 0);
    }
    // bias + DIRECT global stores: 16 lanes x 4B = 64B contiguous segments
    float* og = out + (long long)g * NE * CIN;
    #pragma unroll
    for (int mt = 0; mt < 2; ++mt)
      #pragma unroll
      for (int nt = 0; nt < 4; ++nt)
        #pragma unroll
        for (int b = 0; b < 4; ++b) {
          int row = mt * 16 + hg * 4 + b;
          if (row < NE)
            og[row * CIN + nt * 16 + lr] = acc[mt][nt][b] + biasv[nt];
        }
  };

  // 2 graphs; one slice reused (same-wave in-order DS ops -> race-free)
  PROC(afa, sl, g0);
  PROC(afb, sl, g0 + 1);
}

extern "C" void kernel_launch(void* const* d_in, const int* in_sizes, int n_in,
                              void* d_out, int out_size, void* d_ws, size_t ws_size,
                              hipStream_t stream) {
  const float* x    = (const float*)d_in[0];
  const float* ew   = (const float*)d_in[1];
  const float* Wrel = (const float*)d_in[2];
  const float* Wroot= (const float*)d_in[3];
  const float* bias = (const float*)d_in[4];
  float* out = (float*)d_out;
  unsigned char* ws = (unsigned char*)d_ws;   // needs 18432 B

  prep_kernel<<<5, 256, 0, stream>>>(ew, Wrel, Wroot, ws);

  const int ngraphs = (in_sizes[0] / CIN) / NE;   // 8192
  const int nblocks = ngraphs / 2;                // 4096 single-wave blocks
  gconv_kernel<<<nblocks, 64, 0, stream>>>(x, bias, ws, out);
}

// Round 20
// 24.212 us; speedup vs baseline: 1.0606x; 1.0606x over previous
//
#include <hip/hip_runtime.h>

#define NE 19
#define CIN 64
#define Z1T_STRIDE 80          // bytes per Z1T row (32 bf16 of 40); 16B-aligned, 2-way banks = free
#define SLICE 5120             // per-wave Z1T slice (64*80)
#define FRAG_BYTES 18432       // LDS frag region: [0,16K) Wc B-frags; [16K,18K) A-mix
#define WAVES 4

typedef float f32x4 __attribute__((ext_vector_type(4)));
typedef __bf16 bf16x4 __attribute__((ext_vector_type(4)));
typedef __bf16 bf16x8 __attribute__((ext_vector_type(8)));

// Native casts -> v_cvt_pk_bf16_f32 (1 instr / 2 values)
__device__ __forceinline__ bf16x8 packW(const float* q) {
  f32x4 a = *(const f32x4*)q;
  f32x4 b = *(const f32x4*)(q + 4);
  bf16x8 h;
  h[0]=(__bf16)a[0]; h[1]=(__bf16)a[1]; h[2]=(__bf16)a[2]; h[3]=(__bf16)a[3];
  h[4]=(__bf16)b[0]; h[5]=(__bf16)b[1]; h[6]=(__bf16)b[2]; h[7]=(__bf16)b[3];
  return h;
}

// SINGLE kernel: 512 blocks x 256 threads (4 waves). Per block: build all W/A
// fragments into LDS once (one __syncthreads), then each wave runs the proven
// R18 pipeline on 4 graphs (lookahead-1 x prefetch, all compute in MFMA,
// direct 64B-segment stores). Deletes the prep dispatch + stream gap; W-frag
// L2 amplification is per-block (512 x 32KB = 16MB), not per-wave (R14's bug).
// out = A@(X@Wrel^T) + X@Wroot^T + bias
// launch_bounds (256,2): VGPR cap 128 (cap = 256/min_waves; >=4 clamps to 64
// and spills — R12).
__global__ __launch_bounds__(256, 2) void gconv_kernel(
    const float* __restrict__ x, const float* __restrict__ ew,
    const float* __restrict__ Wrel, const float* __restrict__ Wroot,
    const float* __restrict__ bias, float* __restrict__ out)
{
  __shared__ __align__(16) unsigned char sl[FRAG_BYTES + WAVES * SLICE];  // 38912 B

  const int t = threadIdx.x;
  const int lane = t & 63;
  const int wv = t >> 6;
  const int g0 = blockIdx.x * (4 * WAVES) + wv * 4;   // wave owns g0..g0+3
  const int lr = lane & 15, hg = lane >> 4;
  unsigned char* z1 = sl + FRAG_BYTES + wv * SLICE;
  const bf16x8* frB = (const bf16x8*)sl;

  // ---- (1) x prefetch for the first two graphs (HBM latency starts now)
  auto LOADAF = [&](bf16x8 af[2][2], int g) {
    const float* xg = x + (long long)g * NE * CIN;
    #pragma unroll
    for (int mt = 0; mt < 2; ++mt) {
      int rr = mt * 16 + lr; if (rr > NE - 1) rr = NE - 1;  // dup rows, stores guarded
      const float* xr = xg + rr * CIN + hg * 8;
      #pragma unroll
      for (int kt = 0; kt < 2; ++kt) af[mt][kt] = packW(xr + kt * 32);
    }
  };
  bf16x8 afa[2][2], afb[2][2];
  LOADAF(afa, g0);
  LOADAF(afb, g0 + 1);

  // ---- (2) block-level frag build into LDS (replaces the prep kernel).
  // B-frag fid = ((p*2+kt)*4+nt)*64+flane, p0=Wrel p1=Wroot.
  #pragma unroll
  for (int i = 0; i < 4; ++i) {
    int fid = i * 256 + t;
    int p = fid >> 9, kt = (fid >> 8) & 1, nt = (fid >> 6) & 3, fl = fid & 63;
    const float* Wsrc = p ? Wroot : Wrel;
    *(bf16x8*)(sl + fid * 16) =
        packW(Wsrc + (nt * 16 + (fl & 15)) * CIN + kt * 32 + (fl >> 4) * 8);
  }
  if (t < 128) {
    // A-mix A-frag: lane holds A[mt*16+(fl&15)][k=(fl>>4)*8+b], A[i][j]=sp(ew[j*19+i])
    int mt = t >> 6, fl = t & 63;
    int row = mt * 16 + (fl & 15);
    bf16x8 h;
    #pragma unroll
    for (int b = 0; b < 8; ++b) {
      int k = (fl >> 4) * 8 + b;
      float v = 0.0f;
      if (row < NE && k < NE) {
        float z = ew[k * NE + row];
        v = fmaxf(z, 0.0f) + log1pf(expf(-fabsf(z)));
      }
      h[b] = (__bf16)v;
    }
    *(bf16x8*)(sl + 16384 + t * 16) = h;
  }
  __syncthreads();   // the only barrier: frags visible to all 4 waves

  // ---- (3) hoist frags once per wave (18 ds_read_b128)
  bf16x8 bfa[8], bfb[8];
  #pragma unroll
  for (int i = 0; i < 8; ++i) bfa[i] = frB[i * 64 + lane];
  #pragma unroll
  for (int i = 0; i < 8; ++i) bfb[i] = frB[(8 + i) * 64 + lane];
  const bf16x8 afm0 = frB[1024 + lane];
  const bf16x8 afm1 = frB[1088 + lane];
  float biasv[4];
  #pragma unroll
  for (int nt = 0; nt < 4; ++nt) biasv[nt] = bias[nt * 16 + lr];

  // ---- (4) per-graph pipeline: half1 -> Z1T -> half2 -> mix -> DIRECT store
  auto PROC = [&](bf16x8 af[2][2], int g) {
    // half 1: Z1 = X @ Wrel^T
    f32x4 zacc[2][4];
    #pragma unroll
    for (int mt = 0; mt < 2; ++mt)
      #pragma unroll
      for (int nt = 0; nt < 4; ++nt) { zacc[mt][nt][0]=0.f; zacc[mt][nt][1]=0.f; zacc[mt][nt][2]=0.f; zacc[mt][nt][3]=0.f; }
    #pragma unroll
    for (int nt = 0; nt < 4; ++nt)
      #pragma unroll
      for (int mt = 0; mt < 2; ++mt) {
        zacc[mt][nt] = __builtin_amdgcn_mfma_f32_16x16x32_bf16(
            af[mt][0], bfa[nt], zacc[mt][nt], 0, 0, 0);
        zacc[mt][nt] = __builtin_amdgcn_mfma_f32_16x16x32_bf16(
            af[mt][1], bfa[4 + nt], zacc[mt][nt], 0, 0, 0);
      }
    // bounce Z1 -> Z1T[c][j] bf16 (j 19..31 zeroed), 8 ds_write_b64
    #pragma unroll
    for (int nt = 0; nt < 4; ++nt) {
      int c = nt * 16 + lr;
      bf16x4 h0;
      #pragma unroll
      for (int b = 0; b < 4; ++b) h0[b] = (__bf16)zacc[0][nt][b];
      *(bf16x4*)(z1 + c * Z1T_STRIDE + hg * 8) = h0;
      bf16x4 h1;
      #pragma unroll
      for (int b = 0; b < 4; ++b) {
        int j = 16 + hg * 4 + b;
        h1[b] = (j < NE) ? (__bf16)zacc[1][nt][b] : (__bf16)0.0f;
      }
      *(bf16x4*)(z1 + c * Z1T_STRIDE + 32 + hg * 8) = h1;
    }

    // half 2: acc = X @ Wroot^T (independent of the bounce -> overlaps it)
    f32x4 acc[2][4];
    #pragma unroll
    for (int mt = 0; mt < 2; ++mt)
      #pragma unroll
      for (int nt = 0; nt < 4; ++nt) { acc[mt][nt][0]=0.f; acc[mt][nt][1]=0.f; acc[mt][nt][2]=0.f; acc[mt][nt][3]=0.f; }
    #pragma unroll
    for (int nt = 0; nt < 4; ++nt)
      #pragma unroll
      for (int mt = 0; mt < 2; ++mt) {
        acc[mt][nt] = __builtin_amdgcn_mfma_f32_16x16x32_bf16(
            af[mt][0], bfb[nt], acc[mt][nt], 0, 0, 0);
        acc[mt][nt] = __builtin_amdgcn_mfma_f32_16x16x32_bf16(
            af[mt][1], bfb[4 + nt], acc[mt][nt], 0, 0, 0);
      }
    // mix as MFMA: acc += A @ Z1
    #pragma unroll
    for (int nt = 0; nt < 4; ++nt) {
      bf16x8 zf = *(const bf16x8*)(z1 + (nt * 16 + lr) * Z1T_STRIDE + hg * 16);
      acc[0][nt] = __builtin_amdgcn_mfma_f32_16x16x32_bf16(afm0, zf, acc[0][nt], 0, 0, 0);
      acc[1][nt] = __builtin_amdgcn_mfma_f32_16x16x32_bf16(afm1, zf, acc[1][nt], 0, 0, 0);
    }
    // bias + DIRECT global stores: 16 lanes x 4B = 64B contiguous segments
    float* og = out + (long long)g * NE * CIN;
    #pragma unroll
    for (int mt = 0; mt < 2; ++mt)
      #pragma unroll
      for (int nt = 0; nt < 4; ++nt)
        #pragma unroll
        for (int b = 0; b < 4; ++b) {
          int row = mt * 16 + hg * 4 + b;
          if (row < NE)
            og[row * CIN + nt * 16 + lr] = acc[mt][nt][b] + biasv[nt];
        }
  };

  // 4 graphs, lookahead-1 x prefetch; slice reuse is race-free (same-wave
  // DS ops execute in program order).
  PROC(afa, g0);
  LOADAF(afa, g0 + 2);
  PROC(afb, g0 + 1);
  LOADAF(afb, g0 + 3);
  PROC(afa, g0 + 2);
  PROC(afb, g0 + 3);
}

extern "C" void kernel_launch(void* const* d_in, const int* in_sizes, int n_in,
                              void* d_out, int out_size, void* d_ws, size_t ws_size,
                              hipStream_t stream) {
  const float* x    = (const float*)d_in[0];
  const float* ew   = (const float*)d_in[1];
  const float* Wrel = (const float*)d_in[2];
  const float* Wroot= (const float*)d_in[3];
  const float* bias = (const float*)d_in[4];
  float* out = (float*)d_out;

  const int ngraphs = (in_sizes[0] / CIN) / NE;   // 8192
  const int nblocks = ngraphs / 16;               // 512 blocks x 4 waves x 4 graphs
  gconv_kernel<<<nblocks, 256, 0, stream>>>(x, ew, Wrel, Wroot, bias, out);
}

// Round 21
// 22.253 us; speedup vs baseline: 1.1540x; 1.0880x over previous
//
#include <hip/hip_runtime.h>

#define NE 19
#define CIN 64
#define Z1T_STRIDE 80          // bytes per Z1T row (32 bf16 of 40); 16B-aligned, 2-way banks = free
#define SLICE 5120             // per-wave Z1T slice (64*80)
#define FRAG_BYTES 18432       // LDS frag region: [0,16K) Wc B-frags; [16K,18K) A-mix
#define WAVES 8
#define GPW 4                  // graphs per wave

typedef float f32x4 __attribute__((ext_vector_type(4)));
typedef __bf16 bf16x4 __attribute__((ext_vector_type(4)));
typedef __bf16 bf16x8 __attribute__((ext_vector_type(8)));

// Native casts -> v_cvt_pk_bf16_f32 (1 instr / 2 values)
__device__ __forceinline__ bf16x8 packW(const float* q) {
  f32x4 a = *(const f32x4*)q;
  f32x4 b = *(const f32x4*)(q + 4);
  bf16x8 h;
  h[0]=(__bf16)a[0]; h[1]=(__bf16)a[1]; h[2]=(__bf16)a[2]; h[3]=(__bf16)a[3];
  h[4]=(__bf16)b[0]; h[5]=(__bf16)b[1]; h[6]=(__bf16)b[2]; h[7]=(__bf16)b[3];
  return h;
}

// SINGLE kernel: 256 blocks x 512 threads (8 waves) x 4 graphs/wave = 8192.
// 1 block/CU, 2 waves/SIMD (R20's sweet spot), frag build per block (256
// builds vs R20's 512), lookahead-2 x prefetch (3 graphs in flight before
// first compute -> deeper MLP against memory-system queueing).
// out = A@(X@Wrel^T) + X@Wroot^T + bias, all compute in MFMA, one barrier.
// launch_bounds (512,2): VGPR cap 128 (cap = 256/min_waves; >=4 clamps to 64
// and spills — R12).
__global__ __launch_bounds__(512, 2) void gconv_kernel(
    const float* __restrict__ x, const float* __restrict__ ew,
    const float* __restrict__ Wrel, const float* __restrict__ Wroot,
    const float* __restrict__ bias, float* __restrict__ out)
{
  __shared__ __align__(16) unsigned char sl[FRAG_BYTES + WAVES * SLICE];  // 59392 B

  const int t = threadIdx.x;
  const int lane = t & 63;
  const int wv = t >> 6;
  const int g0 = blockIdx.x * (WAVES * GPW) + wv * GPW;   // wave owns g0..g0+3
  const int lr = lane & 15, hg = lane >> 4;
  unsigned char* z1 = sl + FRAG_BYTES + wv * SLICE;
  const bf16x8* frB = (const bf16x8*)sl;

  // ---- (1) lookahead-2 x prefetch: 3 graphs' loads in flight before compute
  auto LOADAF = [&](bf16x8 af[2][2], int g) {
    const float* xg = x + (long long)g * NE * CIN;
    #pragma unroll
    for (int mt = 0; mt < 2; ++mt) {
      int rr = mt * 16 + lr; if (rr > NE - 1) rr = NE - 1;  // dup rows, stores guarded
      const float* xr = xg + rr * CIN + hg * 8;
      #pragma unroll
      for (int kt = 0; kt < 2; ++kt) af[mt][kt] = packW(xr + kt * 32);
    }
  };
  bf16x8 afa[2][2], afb[2][2], afc[2][2];
  LOADAF(afa, g0);
  LOADAF(afb, g0 + 1);
  LOADAF(afc, g0 + 2);

  // ---- (2) block-level frag build into LDS (once per block).
  // B-frag fid = ((p*2+kt)*4+nt)*64+flane, p0=Wrel p1=Wroot.
  #pragma unroll
  for (int i = 0; i < 2; ++i) {
    int fid = i * 512 + t;
    int p = fid >> 9, kt = (fid >> 8) & 1, nt = (fid >> 6) & 3, fl = fid & 63;
    const float* Wsrc = p ? Wroot : Wrel;
    *(bf16x8*)(sl + fid * 16) =
        packW(Wsrc + (nt * 16 + (fl & 15)) * CIN + kt * 32 + (fl >> 4) * 8);
  }
  if (t < 128) {
    // A-mix A-frag: lane holds A[mt*16+(fl&15)][k=(fl>>4)*8+b], A[i][j]=sp(ew[j*19+i])
    int mt = t >> 6, fl = t & 63;
    int row = mt * 16 + (fl & 15);
    bf16x8 h;
    #pragma unroll
    for (int b = 0; b < 8; ++b) {
      int k = (fl >> 4) * 8 + b;
      float v = 0.0f;
      if (row < NE && k < NE) {
        float z = ew[k * NE + row];
        v = fmaxf(z, 0.0f) + log1pf(expf(-fabsf(z)));
      }
      h[b] = (__bf16)v;
    }
    *(bf16x8*)(sl + 16384 + t * 16) = h;
  }
  __syncthreads();   // the only barrier: frags visible to all waves

  // ---- (3) hoist frags once per wave (18 ds_read_b128)
  bf16x8 bfa[8], bfb[8];
  #pragma unroll
  for (int i = 0; i < 8; ++i) bfa[i] = frB[i * 64 + lane];
  #pragma unroll
  for (int i = 0; i < 8; ++i) bfb[i] = frB[(8 + i) * 64 + lane];
  const bf16x8 afm0 = frB[1024 + lane];
  const bf16x8 afm1 = frB[1088 + lane];
  float biasv[4];
  #pragma unroll
  for (int nt = 0; nt < 4; ++nt) biasv[nt] = bias[nt * 16 + lr];

  // ---- (4) per-graph pipeline: half1 -> Z1T -> half2 -> mix -> DIRECT store
  auto PROC = [&](bf16x8 af[2][2], int g) {
    // half 1: Z1 = X @ Wrel^T
    f32x4 zacc[2][4];
    #pragma unroll
    for (int mt = 0; mt < 2; ++mt)
      #pragma unroll
      for (int nt = 0; nt < 4; ++nt) { zacc[mt][nt][0]=0.f; zacc[mt][nt][1]=0.f; zacc[mt][nt][2]=0.f; zacc[mt][nt][3]=0.f; }
    #pragma unroll
    for (int nt = 0; nt < 4; ++nt)
      #pragma unroll
      for (int mt = 0; mt < 2; ++mt) {
        zacc[mt][nt] = __builtin_amdgcn_mfma_f32_16x16x32_bf16(
            af[mt][0], bfa[nt], zacc[mt][nt], 0, 0, 0);
        zacc[mt][nt] = __builtin_amdgcn_mfma_f32_16x16x32_bf16(
            af[mt][1], bfa[4 + nt], zacc[mt][nt], 0, 0, 0);
      }
    // bounce Z1 -> Z1T[c][j] bf16 (j 19..31 zeroed), 8 ds_write_b64
    #pragma unroll
    for (int nt = 0; nt < 4; ++nt) {
      int c = nt * 16 + lr;
      bf16x4 h0;
      #pragma unroll
      for (int b = 0; b < 4; ++b) h0[b] = (__bf16)zacc[0][nt][b];
      *(bf16x4*)(z1 + c * Z1T_STRIDE + hg * 8) = h0;
      bf16x4 h1;
      #pragma unroll
      for (int b = 0; b < 4; ++b) {
        int j = 16 + hg * 4 + b;
        h1[b] = (j < NE) ? (__bf16)zacc[1][nt][b] : (__bf16)0.0f;
      }
      *(bf16x4*)(z1 + c * Z1T_STRIDE + 32 + hg * 8) = h1;
    }

    // half 2: acc = X @ Wroot^T (independent of the bounce -> overlaps it)
    f32x4 acc[2][4];
    #pragma unroll
    for (int mt = 0; mt < 2; ++mt)
      #pragma unroll
      for (int nt = 0; nt < 4; ++nt) { acc[mt][nt][0]=0.f; acc[mt][nt][1]=0.f; acc[mt][nt][2]=0.f; acc[mt][nt][3]=0.f; }
    #pragma unroll
    for (int nt = 0; nt < 4; ++nt)
      #pragma unroll
      for (int mt = 0; mt < 2; ++mt) {
        acc[mt][nt] = __builtin_amdgcn_mfma_f32_16x16x32_bf16(
            af[mt][0], bfb[nt], acc[mt][nt], 0, 0, 0);
        acc[mt][nt] = __builtin_amdgcn_mfma_f32_16x16x32_bf16(
            af[mt][1], bfb[4 + nt], acc[mt][nt], 0, 0, 0);
      }
    // mix as MFMA: acc += A @ Z1
    #pragma unroll
    for (int nt = 0; nt < 4; ++nt) {
      bf16x8 zf = *(const bf16x8*)(z1 + (nt * 16 + lr) * Z1T_STRIDE + hg * 16);
      acc[0][nt] = __builtin_amdgcn_mfma_f32_16x16x32_bf16(afm0, zf, acc[0][nt], 0, 0, 0);
      acc[1][nt] = __builtin_amdgcn_mfma_f32_16x16x32_bf16(afm1, zf, acc[1][nt], 0, 0, 0);
    }
    // bias + DIRECT global stores: 16 lanes x 4B = 64B contiguous segments
    float* og = out + (long long)g * NE * CIN;
    #pragma unroll
    for (int mt = 0; mt < 2; ++mt)
      #pragma unroll
      for (int nt = 0; nt < 4; ++nt)
        #pragma unroll
        for (int b = 0; b < 4; ++b) {
          int row = mt * 16 + hg * 4 + b;
          if (row < NE)
            og[row * CIN + nt * 16 + lr] = acc[mt][nt][b] + biasv[nt];
        }
  };

  // 4 graphs, lookahead-2; slice reuse race-free (same-wave DS program order)
  PROC(afa, g0);
  LOADAF(afa, g0 + 3);
  PROC(afb, g0 + 1);
  PROC(afc, g0 + 2);
  PROC(afa, g0 + 3);
}

extern "C" void kernel_launch(void* const* d_in, const int* in_sizes, int n_in,
                              void* d_out, int out_size, void* d_ws, size_t ws_size,
                              hipStream_t stream) {
  const float* x    = (const float*)d_in[0];
  const float* ew   = (const float*)d_in[1];
  const float* Wrel = (const float*)d_in[2];
  const float* Wroot= (const float*)d_in[3];
  const float* bias = (const float*)d_in[4];
  float* out = (float*)d_out;

  const int ngraphs = (in_sizes[0] / CIN) / NE;   // 8192
  const int nblocks = ngraphs / (WAVES * GPW);    // 256 blocks, 1/CU
  gconv_kernel<<<nblocks, 512, 0, stream>>>(x, ew, Wrel, Wroot, bias, out);
}